// Round 9
// baseline (708.723 us; speedup 1.0000x reference)
//
#include <hip/hip_runtime.h>
#include <math.h>
#include <float.h>
#include <limits.h>

#define BN      32768   // B*N query rows
#define D_IN    1024
#define E_DIM   128
#define CB_N    8192

typedef _Float16 f16x8  __attribute__((ext_vector_type(8)));
typedef _Float16 f16x4  __attribute__((ext_vector_type(4)));
typedef float    f32x4  __attribute__((ext_vector_type(4)));
typedef float    f32x16 __attribute__((ext_vector_type(16)));

// Workspace:
//   pb  : [CB_N/32][8][64][8] f16   2 MB  (ncb*256 hi, 32x32x16 B-frag packed)
//   plb : same                      2 MB  (lo)
//   rph : [32*8][64][8] f16         0.25 MB (rp*64 hi, 16x16x32 B-frag, phase 1)
//   rpl : same                      0.25 MB

// ---------------------------------------------------------------------------
// Kernel 1: packs.
//  blocks [0,256):   codebook normalize (scale 256) + 32x32x16 B-frag pack
//                    B[n=lane&31][k=(lane>>5)*8+j] per 16-k step
//  blocks [256,320): rp*64 pack in 16x16x32 B-frag layout (validated, phase 1)
// ---------------------------------------------------------------------------
__global__ __launch_bounds__(256) void pack_kernel(
    const float* __restrict__ cb, const float* __restrict__ rp,
    _Float16* __restrict__ pb, _Float16* __restrict__ plb,
    _Float16* __restrict__ rph, _Float16* __restrict__ rpl) {
    const int t = threadIdx.x;
    if (blockIdx.x < 256) {
        __shared__ float L[32][130];
        const int g = blockIdx.x;          // 32-code tile
        // --- norm: code c = t>>3 (0..31), part p = t&7 (16 elems) ---
        const int c = t >> 3, p = t & 7;
        float ss = 0.0f;
        float4 v[4];
#pragma unroll
        for (int i = 0; i < 4; ++i) {
            v[i] = *(const float4*)&cb[(size_t)(g * 32 + c) * E_DIM + p * 16 + i * 4];
            ss += v[i].x * v[i].x + v[i].y * v[i].y + v[i].z * v[i].z + v[i].w * v[i].w;
        }
#pragma unroll
        for (int m = 1; m < 8; m <<= 1) ss += __shfl_xor(ss, m);
        const float inv = 256.0f / fmaxf(sqrtf(ss), 1e-12f);
#pragma unroll
        for (int i = 0; i < 4; ++i) {
            L[c][p * 16 + i * 4 + 0] = v[i].x * inv;
            L[c][p * 16 + i * 4 + 1] = v[i].y * inv;
            L[c][p * 16 + i * 4 + 2] = v[i].z * inv;
            L[c][p * 16 + i * 4 + 3] = v[i].w * inv;
        }
        __syncthreads();

        // --- pack: thread covers 2 ksteps x 1 lane-slot ---
        const int lane = t & 63;
        const int n32  = lane & 31, kh = lane >> 5;
#pragma unroll
        for (int ks2 = 0; ks2 < 2; ++ks2) {
            const int ks = (t >> 6) * 2 + ks2;   // 0..7
            f16x8 h, l;
#pragma unroll
            for (int j = 0; j < 8; ++j) {
                const float vv = L[n32][ks * 16 + kh * 8 + j];
                const _Float16 hv = (_Float16)vv;
                h[j] = hv;
                l[j] = (_Float16)(vv - (float)hv);
            }
            const size_t off = ((size_t)(g * 8 + ks) * 64 + lane) * 8;
            *(f16x8*)&pb[off]  = h;
            *(f16x8*)&plb[off] = l;
        }
    } else {
        const int w = t >> 6, lane = t & 63;
        const int b = (blockIdx.x - 256) * 4 + w;      // 0..255
        const int kb = b >> 3, nt = b & 7;
        const int quad = lane >> 4, col = lane & 15;
        f16x8 h, l;
#pragma unroll
        for (int j = 0; j < 8; ++j) {
            const float v = rp[(size_t)(kb * 32 + quad * 8 + j) * E_DIM + nt * 16 + col] * 64.0f;
            const _Float16 hv = (_Float16)v;
            h[j] = hv;
            l[j] = (_Float16)(v - (float)hv);
        }
        const size_t off = ((size_t)b * 64 + lane) * 8;
        *(f16x8*)&rph[off] = h;
        *(f16x8*)&rpl[off] = l;
    }
}

// ---------------------------------------------------------------------------
// Kernel 2: FUSED proj + scores + argmax. 64 q/block, grid 512 (2 blocks/CU).
// Phase 1: unchanged validated 16x16x32 proj -> LDS P [64][132] f32.
// Phase 2: 32x32x16 MFMA. Wave = (wq: 32-q tile, wc: code half). Per 32-code
// tile: 24 MFMAs (3 passes x 8 ksteps), 3 independent f32x16 chains,
// single-buffered B (regs don't allow dbuf at 2 waves/SIMD).
// C/D layout (m74/m101): col=lane&31, row=(reg&3)+8*(reg>>2)+4*(lane>>5).
// ---------------------------------------------------------------------------
#define PAD_ROW 40    // phase-1 staging row stride (halfwords)
#define PPITCH  132   // P row pitch (dwords)

__global__ __launch_bounds__(256, 2) void fused_kernel(
    const float* __restrict__ x,
    const _Float16* __restrict__ rph, const _Float16* __restrict__ rpl,
    const _Float16* __restrict__ pb, const _Float16* __restrict__ plb,
    int* __restrict__ out) {
    __shared__ _Float16 Ah[64 * PAD_ROW];
    __shared__ _Float16 Al[64 * PAD_ROW];
    __shared__ float    P[64 * PPITCH];
    __shared__ float    ls[4][32];
    __shared__ int      li[4][32];

    const int tid  = threadIdx.x;
    const int lane = tid & 63;
    const int w    = tid >> 6;
    const int quad = lane >> 4, col = lane & 15;
    const int qb   = blockIdx.x * 64;

    // ======================= Phase 1: projection (validated) =================
    const int srow = tid >> 3;        // 0..31
    const int skc  = (tid & 7) * 4;   // 0,4,..,28

    f32x4 acc[4][2];
#pragma unroll
    for (int mt = 0; mt < 4; ++mt)
#pragma unroll
        for (int h = 0; h < 2; ++h) acc[mt][h] = (f32x4){0.f, 0.f, 0.f, 0.f};

    float4 pre[2];
#pragma unroll
    for (int i = 0; i < 2; ++i)
        pre[i] = *(const float4*)&x[(size_t)(qb + srow + 32 * i) * D_IN + skc];

    for (int kb = 0; kb < 32; ++kb) {
#pragma unroll
        for (int i = 0; i < 2; ++i) {
            const float vv[4] = {pre[i].x, pre[i].y, pre[i].z, pre[i].w};
            f16x4 h4, l4;
#pragma unroll
            for (int j = 0; j < 4; ++j) {
                const float v = vv[j] * 512.0f;
                const _Float16 hv = (_Float16)v;
                h4[j] = hv;
                l4[j] = (_Float16)(v - (float)hv);
            }
            const int base = (srow + 32 * i) * PAD_ROW + skc;
            *(f16x4*)&Ah[base] = h4;
            *(f16x4*)&Al[base] = l4;
        }
        __syncthreads();

        if (kb + 1 < 32) {
#pragma unroll
            for (int i = 0; i < 2; ++i)
                pre[i] = *(const float4*)&x[(size_t)(qb + srow + 32 * i) * D_IN + (kb + 1) * 32 + skc];
        }

        f16x8 bh1[2], bl1[2];
#pragma unroll
        for (int h = 0; h < 2; ++h) {
            const int nt = w * 2 + h;
            const size_t off = ((size_t)(kb * 8 + nt) * 64 + lane) * 8;
            bh1[h] = *(const f16x8*)&rph[off];
            bl1[h] = *(const f16x8*)&rpl[off];
        }

        f16x8 ah1[4], al1[4];
#pragma unroll
        for (int mt = 0; mt < 4; ++mt) {
            const int base = (mt * 16 + col) * PAD_ROW + quad * 8;
            ah1[mt] = *(const f16x8*)&Ah[base];
            al1[mt] = *(const f16x8*)&Al[base];
        }

#pragma unroll
        for (int mt = 0; mt < 4; ++mt)
#pragma unroll
            for (int h = 0; h < 2; ++h)
                acc[mt][h] = __builtin_amdgcn_mfma_f32_16x16x32_f16(ah1[mt], bh1[h], acc[mt][h], 0, 0, 0);
#pragma unroll
        for (int mt = 0; mt < 4; ++mt)
#pragma unroll
            for (int h = 0; h < 2; ++h)
                acc[mt][h] = __builtin_amdgcn_mfma_f32_16x16x32_f16(ah1[mt], bl1[h], acc[mt][h], 0, 0, 0);
#pragma unroll
        for (int mt = 0; mt < 4; ++mt)
#pragma unroll
            for (int h = 0; h < 2; ++h)
                acc[mt][h] = __builtin_amdgcn_mfma_f32_16x16x32_f16(al1[mt], bh1[h], acc[mt][h], 0, 0, 0);

        __syncthreads();
    }

    // proj*16 (f32) -> LDS P [query][k].
#pragma unroll
    for (int mt = 0; mt < 4; ++mt)
#pragma unroll
        for (int h = 0; h < 2; ++h)
#pragma unroll
            for (int r = 0; r < 4; ++r) {
                const int row = mt * 16 + quad * 4 + r;
                const int cc  = w * 32 + h * 16 + col;
                P[row * PPITCH + cc] = acc[mt][h][r] * (1.0f / 2048.0f);
            }
    __syncthreads();

    // ======================= Phase 2: 32x32x16 scores + argmax ===============
    const int wq  = w >> 1;        // 32-query tile
    const int wc  = w & 1;         // code half: tiles [wc*128, wc*128+128)
    const int n32 = lane & 31, kh = lane >> 5;

    // A-frags: A[m=lane&31][k=kh*8+j] per kstep, split hi/lo.
    f16x8 ah[8], al[8];
#pragma unroll
    for (int ks = 0; ks < 8; ++ks) {
        const int base = (wq * 32 + n32) * PPITCH + ks * 16 + kh * 8;
        const float4 v0 = *(const float4*)&P[base];
        const float4 v1 = *(const float4*)&P[base + 4];
        const float vv[8] = {v0.x, v0.y, v0.z, v0.w, v1.x, v1.y, v1.z, v1.w};
        f16x8 hh, ll;
#pragma unroll
        for (int j = 0; j < 8; ++j) {
            const _Float16 hv = (_Float16)vv[j];
            hh[j] = hv;
            ll[j] = (_Float16)(vv[j] - (float)hv);
        }
        ah[ks] = hh;
        al[ks] = ll;
    }

    float bs[16];
    int   bi[16];
#pragma unroll
    for (int s = 0; s < 16; ++s) { bs[s] = -FLT_MAX; bi[s] = 0; }

    const int g0 = wc * 128;

#pragma unroll 1
    for (int t = 0; t < 128; ++t) {
        const int g = g0 + t;
        f16x8 bh[8], bl[8];
#pragma unroll
        for (int ks = 0; ks < 8; ++ks) {
            const size_t off = ((size_t)(g * 8 + ks) * 64 + lane) * 8;
            bh[ks] = *(const f16x8*)&pb[off];
            bl[ks] = *(const f16x8*)&plb[off];
        }

        // 3 independent chains: main (hi*hi), c1 (hi*lo), c2 (lo*hi).
        f32x16 am = (f32x16)(0.0f), c1 = (f32x16)(0.0f), c2 = (f32x16)(0.0f);
#pragma unroll
        for (int ks = 0; ks < 8; ++ks) {
            am = __builtin_amdgcn_mfma_f32_32x32x16_f16(ah[ks], bh[ks], am, 0, 0, 0);
            c1 = __builtin_amdgcn_mfma_f32_32x32x16_f16(ah[ks], bl[ks], c1, 0, 0, 0);
            c2 = __builtin_amdgcn_mfma_f32_32x32x16_f16(al[ks], bh[ks], c2, 0, 0, 0);
        }
        const f32x16 s = am + c1 + c2;

        const int code = g * 32 + n32;   // candidate code for ALL 16 C-values of this lane
#pragma unroll
        for (int r = 0; r < 16; ++r) {
            if (s[r] > bs[r]) { bs[r] = s[r]; bi[r] = code; }  // ascending codes: > keeps min idx
        }
    }

    // Reduce 32 code-columns per query row (xor over low 5 lane bits; stays
    // within each 32-lane half, which holds a disjoint row set).
#pragma unroll
    for (int s = 0; s < 16; ++s) {
#pragma unroll
        for (int m = 1; m < 32; m <<= 1) {
            const float os = __shfl_xor(bs[s], m);
            const int   oi = __shfl_xor(bi[s], m);
            if (os > bs[s] || (os == bs[s] && oi < bi[s])) { bs[s] = os; bi[s] = oi; }
        }
    }

    // Writers: lane 0 (rows {0-3,8-11,16-19,24-27}) and lane 32 (rows +4).
    if (n32 == 0) {
#pragma unroll
        for (int r = 0; r < 16; ++r) {
            const int row = (r & 3) + 8 * (r >> 2) + 4 * kh;
            ls[w][row] = bs[r];
            li[w][row] = bi[r];
        }
    }
    __syncthreads();

    // Merge the two code halves per 32-q tile (wc ascending: > keeps min idx).
    if (tid < 64) {
        const int q     = tid;
        const int qtile = q >> 5;
        const int row   = q & 31;
        float s = ls[qtile * 2 + 0][row];
        int   i = li[qtile * 2 + 0][row];
        const float os = ls[qtile * 2 + 1][row];
        if (os > s) { s = os; i = li[qtile * 2 + 1][row]; }
        out[qb + q] = i;
    }
}

// ---------------------------------------------------------------------------
extern "C" void kernel_launch(void* const* d_in, const int* in_sizes, int n_in,
                              void* d_out, int out_size, void* d_ws, size_t ws_size,
                              hipStream_t stream) {
    const float* x  = (const float*)d_in[0];   // [8,4096,1024]
    const float* rp = (const float*)d_in[1];   // [1024,128]
    const float* cb = (const float*)d_in[2];   // [8192,128]
    int* out = (int*)d_out;                    // [8,4096] int32

    _Float16* pb  = (_Float16*)d_ws;                         // 2 MB
    _Float16* plb = pb  + (size_t)CB_N * E_DIM;              // 2 MB
    _Float16* rph = plb + (size_t)CB_N * E_DIM;              // 256 KB
    _Float16* rpl = rph + (size_t)D_IN * E_DIM;              // 256 KB

    pack_kernel<<<320, 256, 0, stream>>>(cb, rp, pb, plb, rph, rpl);
    fused_kernel<<<BN / 64, 256, 0, stream>>>(x, rph, rpl, pb, plb, out);
}